// Round 8
// baseline (342.772 us; speedup 1.0000x reference)
//
#include <hip/hip_runtime.h>

#define T 4096
#define K 4096
#define O 4096
#define E 4
#define BK 64
#define MAXT128 35

typedef __attribute__((ext_vector_type(8))) short bf16x8;
typedef __attribute__((ext_vector_type(4))) float f32x4;

__device__ __forceinline__ unsigned short f2bf(float f) {
  unsigned int u = __float_as_uint(f);
  u += 0x7fffu + ((u >> 16) & 1u);  // RNE
  return (unsigned short)(u >> 16);
}

__device__ __forceinline__ bf16x8 pack8(float4 a, float4 b) {
  union { unsigned int u[4]; bf16x8 v; } r;
  asm("v_cvt_pk_bf16_f32 %0, %1, %2" : "=v"(r.u[0]) : "v"(a.x), "v"(a.y));
  asm("v_cvt_pk_bf16_f32 %0, %1, %2" : "=v"(r.u[1]) : "v"(a.z), "v"(a.w));
  asm("v_cvt_pk_bf16_f32 %0, %1, %2" : "=v"(r.u[2]) : "v"(b.x), "v"(b.y));
  asm("v_cvt_pk_bf16_f32 %0, %1, %2" : "=v"(r.u[3]) : "v"(b.z), "v"(b.w));
  return r.v;
}

// One block, 256 threads. Builds perm, tile tables, persistent schedule
// (XCD 4x8 region map + remainder K-units).
__global__ void build_meta(const int* __restrict__ idx, int* __restrict__ perm,
                           int* __restrict__ meta, int4* __restrict__ t256,
                           int4* __restrict__ t128, int4* __restrict__ sched) {
  const int wave = threadIdx.x >> 6;
  const int lane = threadIdx.x & 63;
  __shared__ int s_off[E + 1];
  __shared__ int rtE[20], rtP[20], rtC[20];
  __shared__ int r_sh;
  int total = 0;
  for (int t0 = 0; t0 < T; t0 += 64)
    total += __popcll(__ballot(idx[t0 + lane] == wave));
  if (lane == 0) s_off[wave + 1] = total;
  __syncthreads();
  if (threadIdx.x == 0) {
    s_off[0] = 0;
    for (int e = 0; e < E; e++) s_off[e + 1] += s_off[e];
  }
  __syncthreads();
  int base = s_off[wave];
  const unsigned long long below = (1ull << lane) - 1ull;
  for (int t0 = 0; t0 < T; t0 += 64) {
    int e = idx[t0 + lane];
    unsigned long long m = __ballot(e == wave);
    if (e == wave) perm[base + __popcll(m & below)] = t0 + lane;
    base += __popcll(m);
  }
  if (threadIdx.x == 0) {
    int n = 0;
    for (int e = 0; e < E; e++) {
      int s = s_off[e], c = s_off[e + 1] - s;
      for (int ro = 0; ro < c; ro += 256) {
        rtE[n] = e; rtP[n] = s + ro; rtC[n] = (c - ro) < 256 ? (c - ro) : 256; n++;
      }
    }
    r_sh = n;
    meta[0] = n * 16;
    int n1 = 0;
    for (int e = 0; e < E; e++) {
      int s = s_off[e], c = s_off[e + 1] - s;
      for (int ro = 0; ro < c; ro += 128)
        t128[n1++] = make_int4(e, s + ro, (c - ro) < 128 ? (c - ro) : 128, 0);
    }
    for (; n1 < MAXT128; n1++) t128[n1] = make_int4(-1, 0, 0, 0);
  }
  __syncthreads();
  const int r = r_sh;  // rowtiles, 16..19
  for (int i = threadIdx.x; i < 16 * r; i += 256)
    t256[i] = make_int4(rtE[i >> 4], rtP[i >> 4], rtC[i >> 4], (i & 15) * 256);
  {
    const int b = threadIdx.x;
    const int ru = r - 16;
    const int xcd = b & 7, s = b >> 3;
    const int rt_ = 4 * (xcd >> 1) + (s >> 3);
    const int nt_ = 8 * (xcd & 1) + (s & 7);
    sched[b * 3 + 0] = make_int4(rt_ * 16 + nt_, 0, 16, 0);
    int sgi = 1, u0 = b * ru, u1 = u0 + ru;
    while (u0 < u1) {
      int tI = 256 + (u0 >> 4), q0 = u0 & 15;
      int avail = 16 - q0, want = u1 - u0;
      int take = want < avail ? want : avail;
      sched[b * 3 + sgi] = make_int4(tI, q0, take, 0);
      sgi++; u0 += take;
    }
    for (; sgi < 3; sgi++) sched[b * 3 + sgi] = make_int4(-1, 0, 0, 0);
  }
}

// Zero the output regions of remainder tiles (atomic-combine targets).
__global__ void zero_rem(const int* __restrict__ meta, const int4* __restrict__ t256,
                         const int* __restrict__ perm, float* __restrict__ out) {
  const int ntiles = meta[0];
  const int tI = 256 + (int)blockIdx.x / 16;
  if (tI >= ntiles) return;
  const int4 td = t256[tI];
  const int rt = (blockIdx.x & 15) * 16 + ((int)threadIdx.x >> 4);
  if (rt >= td.z) return;
  float4* p = (float4*)(out + (size_t)perm[td.y + rt] * O + td.w) + (threadIdx.x & 15) * 4;
  const float4 z = {0.f, 0.f, 0.f, 0.f};
  p[0] = z; p[1] = z; p[2] = z; p[3] = z;
}

// Gather-cast x rows into expert-sorted bf16 order (W stays fp32 now).
__global__ void convert_x(const float* __restrict__ x, const int* __restrict__ perm,
                          ushort4* __restrict__ xg4) {
  const size_t NX4 = (size_t)T * K / 4;
  const size_t stride = (size_t)gridDim.x * blockDim.x;
  for (size_t i = (size_t)blockIdx.x * blockDim.x + threadIdx.x; i < NX4; i += stride) {
    int p = (int)(i >> 10);
    int c = (int)(i & 1023);
    float4 v = *((const float4*)(x + (size_t)perm[p] * K) + c);
    xg4[i] = make_ushort4(f2bf(v.x), f2bf(v.y), f2bf(v.z), f2bf(v.w));
  }
}

// ---------------- persistent 256x256 grouped GEMM, fused B-convert ----------
// A: bf16 from xg via global_load_lds (inverse-swizzled source, linear dest).
// B: fp32 W loaded to regs (C++ float4 -> compiler-tracked waits), cvt_pk to
//    bf16, ds_write_b128 to the SWIZZLED slot (write-side swizzle legal for
//    reg-staging). B half loaded in region h is written in region h+1.
// 2 sync points per K-tile: {VM6; LGKM0; BAR} publishes one half each.
__global__ __launch_bounds__(512, 2)
void gemm8p(const unsigned short* __restrict__ xg, const float* __restrict__ wf,
            const int* __restrict__ perm, const int4* __restrict__ t256,
            const int4* __restrict__ sched, float* __restrict__ out) {
  __shared__ unsigned short lds[65536];  // 128 KiB
  const int bid = blockIdx.x;
  const int tid = threadIdx.x;
  const int wid = tid >> 6, lane = tid & 63;
  const int wr = wid >> 2, wc = wid & 3;  // 2M x 4N waves; per-wave 128x64
  const int kc4 = lane >> 4;
  unsigned short* ldsw = &lds[wid * 512];  // wave-uniform stage base (A)

#define GLL(gp, lp) __builtin_amdgcn_global_load_lds( \
    (const __attribute__((address_space(1))) void*)(gp), \
    (__attribute__((address_space(3))) void*)(lp), 16, 0, 0)
#define GLLA(bo, kh, ko) do { \
    GLL(srcA0 + (ko) + (kh) * 32, ldsw + (bo) + (kh) * 8192); \
    GLL(srcA1 + (ko) + (kh) * 32, ldsw + (bo) + (kh) * 8192 + 4096); \
  } while (0)
// B reg staging: sweep s: row = s*128 + (tid>>2), c4 = tid&3 (8 floats).
#define BLOAD(kh, ko) do { _Pragma("unroll") \
    for (int s = 0; s < 2; ++s) { \
      const float* p_ = srcBF + (size_t)(s * 128 + (tid >> 2)) * K + (ko) + (kh) * 32 + (tid & 3) * 8; \
      bA[s] = *(const float4*)p_; bB[s] = *(const float4*)(p_ + 4); \
    } } while (0)
#define BSTORE(bo, kh) do { _Pragma("unroll") \
    for (int s = 0; s < 2; ++s) \
      *(bf16x8*)&lds[(bo) + 16384 + (kh) * 8192 + bslot[s] * 8] = pack8(bA[s], bB[s]); \
  } while (0)
#define LOADA(dst, bo, ks, mh) do { _Pragma("unroll") \
    for (int mi = 0; mi < 4; ++mi) \
      dst[mi] = *(const bf16x8*)&lds[(bo) + (ks) * 8192 + aoff[mh][mi]]; } while (0)
#define LOADB(dst, bo, ks) do { _Pragma("unroll") \
    for (int ni = 0; ni < 4; ++ni) \
      dst[ni] = *(const bf16x8*)&lds[(bo) + 16384 + (ks) * 8192 + boff[ni]]; } while (0)
#define MFMA16(A, B, mh) do { _Pragma("unroll") \
    for (int mi = 0; mi < 4; ++mi) _Pragma("unroll") \
      for (int ni = 0; ni < 4; ++ni) \
        acc[(mh) * 4 + mi][ni] = __builtin_amdgcn_mfma_f32_16x16x32_bf16( \
            A[mi], B[ni], acc[(mh) * 4 + mi][ni], 0, 0, 0); } while (0)
#define BAR() do { __builtin_amdgcn_s_barrier(); asm volatile("" ::: "memory"); } while (0)
#define LGKM0() asm volatile("s_waitcnt lgkmcnt(0)" ::: "memory")
#define VM6() asm volatile("s_waitcnt vmcnt(6)" ::: "memory")
#define VM4() asm volatile("s_waitcnt vmcnt(4)" ::: "memory")
#define VM0() asm volatile("s_waitcnt vmcnt(0)" ::: "memory")
#define PRIO1() __builtin_amdgcn_s_setprio(1)
#define PRIO0() __builtin_amdgcn_s_setprio(0)

// One K-tile = 2 regions. Region computes cur half; stores the B half loaded
// last region; issues next half's B loads + A gloads; publishes at the end.
#define KTILE(C, X, koe) do { \
    const int ko = (koe); \
    /* R1: compute cur.kh0; store cur.B.kh1; issue nxt.kh0 */ \
    LOADA(afP, C, 0, 0); LOADB(bfP, C, 0); LOADA(afQ, C, 0, 1); \
    BSTORE(C, 1); \
    BLOAD(0, ko); GLLA(X, 0, ko); \
    PRIO1(); MFMA16(afP, bfP, 0); MFMA16(afQ, bfP, 1); PRIO0(); \
    VM6(); LGKM0(); BAR(); \
    /* R2: compute cur.kh1; store nxt.B.kh0; issue nxt.kh1 */ \
    LOADA(afP, C, 1, 0); LOADB(bfQ, C, 1); LOADA(afQ, C, 1, 1); \
    BSTORE(X, 0); \
    BLOAD(1, ko); GLLA(X, 1, ko); \
    PRIO1(); MFMA16(afP, bfQ, 0); MFMA16(afQ, bfQ, 1); PRIO0(); \
    VM6(); LGKM0(); BAR(); \
  } while (0)

  // swizzled fragment offsets (ushort units) — segment-invariant
  int aoff[2][4], boff[4];
#pragma unroll
  for (int mh = 0; mh < 2; ++mh)
#pragma unroll
    for (int mi = 0; mi < 4; ++mi) {
      int r = wr * 128 + mh * 64 + mi * 16 + (lane & 15);
      aoff[mh][mi] = (((r >> 1) << 3) + (((((r & 1) << 2) | kc4)) ^ ((r >> 1) & 7))) * 8;
    }
#pragma unroll
  for (int ni = 0; ni < 4; ++ni) {
    int r = wc * 64 + ni * 16 + (lane & 15);
    boff[ni] = (((r >> 1) << 3) + (((((r & 1) << 2) | kc4)) ^ ((r >> 1) & 7))) * 8;
  }
  // B write slots (same swizzle, per-thread, segment-invariant)
  int bslot[2];
#pragma unroll
  for (int s = 0; s < 2; ++s) {
    int row = s * 128 + (tid >> 2), c4 = tid & 3;
    bslot[s] = ((row >> 1) << 3) + (((((row & 1) << 2) | c4)) ^ ((row >> 1) & 7));
  }

  for (int sg = 0; sg < 3; ++sg) {
    const int4 sd = sched[bid * 3 + sg];
    if (sd.x < 0) break;
    const int4 td = t256[sd.x];
    const int e = td.x, p0 = td.y, rc = td.z, n0 = td.w;
    const int kt0 = sd.y << 2;
    const int nt = sd.z << 2;   // BK-tiles, multiple of 4

    // A staging source decode (slot -> logical row/c4, inverse of read swizzle)
    const unsigned short *srcA0, *srcA1;
    {
      int s0 = tid, s1 = 512 + tid;
      int b0 = s0 >> 3, v0 = (s0 & 7) ^ (b0 & 7);
      int r0 = b0 * 2 + (v0 >> 2), c0 = v0 & 3;
      int b1 = s1 >> 3, v1 = (s1 & 7) ^ (b1 & 7);
      int r1 = b1 * 2 + (v1 >> 2), c1 = v1 & 3;
      int ra0 = r0 < rc ? r0 : rc - 1;
      int ra1 = r1 < rc ? r1 : rc - 1;
      srcA0 = xg + (size_t)(p0 + ra0) * K + c0 * 8;
      srcA1 = xg + (size_t)(p0 + ra1) * K + c1 * 8;
    }
    const float* srcBF = wf + (size_t)e * O * K + (size_t)n0 * K;

    f32x4 acc[8][4] = {};
    bf16x8 afP[4], afQ[4], bfP[4], bfQ[4];
    float4 bA[2], bB[2];

    // prologue: stage buf0 (A both halves via DMA; B.kh0 via regs; B.kh1 pending)
    const int kb = kt0 << 6;
    BLOAD(0, kb);
    GLLA(0, 0, kb); GLLA(0, 1, kb);
    BSTORE(0, 0);          // compiler waits the 4 B loads
    BLOAD(1, kb);          // pending -> first KTILE's BSTORE(C,1)
    VM4(); LGKM0(); BAR(); // A landed (leaves the 4 newest B loads in flight)

    for (int tp = 0; tp < nt; tp += 2) {
      KTILE(0, 32768, ((tp + 1 < nt ? tp + 1 : tp) + kt0) << 6);
      KTILE(32768, 0, ((tp + 2 < nt ? tp + 2 : tp + 1) + kt0) << 6);
    }
    VM0();  // drain stale prefetch before epilogue / next segment

    // epilogue: C layout col=lane&15, row=(lane>>4)*4+reg
    if (sd.z == 16) {
#pragma unroll
      for (int mh = 0; mh < 2; ++mh)
#pragma unroll
        for (int mi = 0; mi < 4; ++mi) {
          const int rbase = wr * 128 + mh * 64 + mi * 16 + (lane >> 4) * 4;
#pragma unroll
          for (int reg = 0; reg < 4; ++reg) {
            const int pr = rbase + reg;
            if (pr < rc) {
              float* orow = out + (size_t)perm[p0 + pr] * O + n0 + wc * 64 + (lane & 15);
#pragma unroll
              for (int ni = 0; ni < 4; ++ni) orow[ni * 16] = acc[mh * 4 + mi][ni][reg];
            }
          }
        }
    } else {
#pragma unroll
      for (int mh = 0; mh < 2; ++mh)
#pragma unroll
        for (int mi = 0; mi < 4; ++mi) {
          const int rbase = wr * 128 + mh * 64 + mi * 16 + (lane >> 4) * 4;
#pragma unroll
          for (int reg = 0; reg < 4; ++reg) {
            const int pr = rbase + reg;
            if (pr < rc) {
              float* orow = out + (size_t)perm[p0 + pr] * O + n0 + wc * 64 + (lane & 15);
#pragma unroll
              for (int ni = 0; ni < 4; ++ni)
                unsafeAtomicAdd(&orow[ni * 16], acc[mh * 4 + mi][ni][reg]);
            }
          }
        }
    }
  }
}

// ---------------- fallback (small ws): 128x128 fp32-source reg-staged ----------------
__global__ __launch_bounds__(256)
void gemm_fb(const float* __restrict__ xf, const float* __restrict__ wf,
             const int* __restrict__ perm, const int4* __restrict__ tiles,
             float* __restrict__ out) {
  __shared__ unsigned short lds_a[128 * 64];
  __shared__ unsigned short lds_b[128 * 64];
  const int4 td = tiles[blockIdx.x];
  if (td.x < 0) return;
  const int e = td.x, p0 = td.y, rc = td.z;
  const int n0 = blockIdx.y * 128;
  const int wave = threadIdx.x >> 6, lane = threadIdx.x & 63;
  const int wr = wave >> 1, wc = wave & 1;
  f32x4 acc[4][4] = {};
  const float* wf_base = wf + (size_t)e * O * K + (size_t)n0 * K;
  for (int k0 = 0; k0 < K; k0 += 64) {
    if (k0) __syncthreads();
#pragma unroll
    for (int i = 0; i < 8; i++) {
      int l4 = i * 256 + (int)threadIdx.x;
      int row = l4 >> 4;
      int c4 = (l4 & 15) << 2;
      int ra = row < rc ? row : (rc - 1);
      const float4 va = *(const float4*)(xf + (size_t)perm[p0 + ra] * K + k0 + c4);
      *(ushort4*)&lds_a[row * 64 + c4] = make_ushort4(f2bf(va.x), f2bf(va.y), f2bf(va.z), f2bf(va.w));
      const float4 vb = *(const float4*)(wf_base + (size_t)row * K + k0 + c4);
      *(ushort4*)&lds_b[row * 64 + c4] = make_ushort4(f2bf(vb.x), f2bf(vb.y), f2bf(vb.z), f2bf(vb.w));
    }
    __syncthreads();
#pragma unroll
    for (int ks = 0; ks < 2; ks++) {
      bf16x8 a2[4], b2[4];
#pragma unroll
      for (int mi = 0; mi < 4; mi++)
        a2[mi] = *(const bf16x8*)&lds_a[(wr * 64 + mi * 16 + (lane & 15)) * 64 + ks * 32 + (lane >> 4) * 8];
#pragma unroll
      for (int ni = 0; ni < 4; ni++)
        b2[ni] = *(const bf16x8*)&lds_b[(wc * 64 + ni * 16 + (lane & 15)) * 64 + ks * 32 + (lane >> 4) * 8];
#pragma unroll
      for (int mi = 0; mi < 4; mi++)
#pragma unroll
        for (int ni = 0; ni < 4; ni++)
          acc[mi][ni] = __builtin_amdgcn_mfma_f32_16x16x32_bf16(a2[mi], b2[ni], acc[mi][ni], 0, 0, 0);
    }
  }
#pragma unroll
  for (int mi = 0; mi < 4; mi++) {
    const int rb = wr * 64 + mi * 16 + (lane >> 4) * 4;
#pragma unroll
    for (int reg = 0; reg < 4; reg++) {
      const int rt = rb + reg;
      if (rt < rc) {
        float* orow = out + (size_t)perm[p0 + rt] * O + n0 + wc * 64 + (lane & 15);
#pragma unroll
        for (int ni = 0; ni < 4; ni++) orow[ni * 16] = acc[mi][ni][reg];
      }
    }
  }
}

extern "C" void kernel_launch(void* const* d_in, const int* in_sizes, int n_in,
                              void* d_out, int out_size, void* d_ws, size_t ws_size,
                              hipStream_t stream) {
  const float* x = (const float*)d_in[0];
  const float* w = (const float*)d_in[1];
  const int* idx = (const int*)d_in[2];
  float* out = (float*)d_out;
  char* ws = (char*)d_ws;

  int* perm = (int*)ws;                        // 16 KB
  int* meta = (int*)(ws + 16384);              // 16 B
  int4* t256 = (int4*)(ws + 16640);            // 4864 B
  int4* t128 = (int4*)(ws + 22528);            // 560 B
  int4* sched = (int4*)(ws + 24576);           // 12 KB
  unsigned short* xg = (unsigned short*)(ws + 65536);  // 32 MB bf16
  const size_t need = 65536 + (size_t)T * K * 2;

  build_meta<<<1, 256, 0, stream>>>(idx, perm, meta, t256, t128, sched);
  if (ws_size >= need) {
    zero_rem<<<768, 256, 0, stream>>>(meta, t256, perm, out);
    convert_x<<<2048, 256, 0, stream>>>(x, perm, (ushort4*)xg);
    gemm8p<<<256, 512, 0, stream>>>(xg, w, perm, t256, sched, out);
  } else {
    gemm_fb<<<dim3(MAXT128, 32), 256, 0, stream>>>(x, w, perm, t128, out);
  }
}

// Round 9
// 332.398 us; speedup vs baseline: 1.0312x; 1.0312x over previous
//
#include <hip/hip_runtime.h>

#define T 4096
#define K 4096
#define O 4096
#define E 4
#define MAXT128 35

typedef __attribute__((ext_vector_type(8))) short bf16x8;
typedef __attribute__((ext_vector_type(4))) float f32x4;

__device__ __forceinline__ unsigned short f2bf(float f) {
  unsigned int u = __float_as_uint(f);
  u += 0x7fffu + ((u >> 16) & 1u);  // RNE
  return (unsigned short)(u >> 16);
}

__device__ __forceinline__ bf16x8 pack8(float4 a, float4 b) {
  union { unsigned int u[4]; bf16x8 v; } r;
  asm("v_cvt_pk_bf16_f32 %0, %1, %2" : "=v"(r.u[0]) : "v"(a.x), "v"(a.y));
  asm("v_cvt_pk_bf16_f32 %0, %1, %2" : "=v"(r.u[1]) : "v"(a.z), "v"(a.w));
  asm("v_cvt_pk_bf16_f32 %0, %1, %2" : "=v"(r.u[2]) : "v"(b.x), "v"(b.y));
  asm("v_cvt_pk_bf16_f32 %0, %1, %2" : "=v"(r.u[3]) : "v"(b.z), "v"(b.w));
  return r.v;
}

// One block, 256 threads. perm, tile tables, persistent schedule
// (XCD 4x8 region map + remainder K-units; K-unit = 256 k = 8 steps of 32).
__global__ void build_meta(const int* __restrict__ idx, int* __restrict__ perm,
                           int* __restrict__ meta, int4* __restrict__ t256,
                           int4* __restrict__ t128, int4* __restrict__ sched) {
  const int wave = threadIdx.x >> 6;
  const int lane = threadIdx.x & 63;
  __shared__ int s_off[E + 1];
  __shared__ int rtE[20], rtP[20], rtC[20];
  __shared__ int r_sh;
  int total = 0;
  for (int t0 = 0; t0 < T; t0 += 64)
    total += __popcll(__ballot(idx[t0 + lane] == wave));
  if (lane == 0) s_off[wave + 1] = total;
  __syncthreads();
  if (threadIdx.x == 0) {
    s_off[0] = 0;
    for (int e = 0; e < E; e++) s_off[e + 1] += s_off[e];
  }
  __syncthreads();
  int base = s_off[wave];
  const unsigned long long below = (1ull << lane) - 1ull;
  for (int t0 = 0; t0 < T; t0 += 64) {
    int e = idx[t0 + lane];
    unsigned long long m = __ballot(e == wave);
    if (e == wave) perm[base + __popcll(m & below)] = t0 + lane;
    base += __popcll(m);
  }
  if (threadIdx.x == 0) {
    int n = 0;
    for (int e = 0; e < E; e++) {
      int s = s_off[e], c = s_off[e + 1] - s;
      for (int ro = 0; ro < c; ro += 256) {
        rtE[n] = e; rtP[n] = s + ro; rtC[n] = (c - ro) < 256 ? (c - ro) : 256; n++;
      }
    }
    r_sh = n;
    meta[0] = n * 16;
    int n1 = 0;
    for (int e = 0; e < E; e++) {
      int s = s_off[e], c = s_off[e + 1] - s;
      for (int ro = 0; ro < c; ro += 128)
        t128[n1++] = make_int4(e, s + ro, (c - ro) < 128 ? (c - ro) : 128, 0);
    }
    for (; n1 < MAXT128; n1++) t128[n1] = make_int4(-1, 0, 0, 0);
  }
  __syncthreads();
  const int r = r_sh;  // rowtiles, 16..19
  for (int i = threadIdx.x; i < 16 * r; i += 256)
    t256[i] = make_int4(rtE[i >> 4], rtP[i >> 4], rtC[i >> 4], (i & 15) * 256);
  {
    const int b = threadIdx.x;
    const int ru = r - 16;
    const int xcd = b & 7, s = b >> 3;
    const int rt_ = 4 * (xcd >> 1) + (s >> 3);
    const int nt_ = 8 * (xcd & 1) + (s & 7);
    sched[b * 3 + 0] = make_int4(rt_ * 16 + nt_, 0, 16, 0);
    int sgi = 1, u0 = b * ru, u1 = u0 + ru;
    while (u0 < u1) {
      int tI = 256 + (u0 >> 4), q0 = u0 & 15;
      int avail = 16 - q0, want = u1 - u0;
      int take = want < avail ? want : avail;
      sched[b * 3 + sgi] = make_int4(tI, q0, take, 0);
      sgi++; u0 += take;
    }
    for (; sgi < 3; sgi++) sched[b * 3 + sgi] = make_int4(-1, 0, 0, 0);
  }
}

// Zero the output regions of remainder tiles (atomic-combine targets).
__global__ void zero_rem(const int* __restrict__ meta, const int4* __restrict__ t256,
                         const int* __restrict__ perm, float* __restrict__ out) {
  const int ntiles = meta[0];
  const int tI = 256 + (int)blockIdx.x / 16;
  if (tI >= ntiles) return;
  const int4 td = t256[tI];
  const int rt = (blockIdx.x & 15) * 16 + ((int)threadIdx.x >> 4);
  if (rt >= td.z) return;
  float4* p = (float4*)(out + (size_t)perm[td.y + rt] * O + td.w) + (threadIdx.x & 15) * 4;
  const float4 z = {0.f, 0.f, 0.f, 0.f};
  p[0] = z; p[1] = z; p[2] = z; p[3] = z;
}

// Gather-cast x rows into expert-sorted bf16 order (W stays fp32).
__global__ void convert_x(const float* __restrict__ x, const int* __restrict__ perm,
                          ushort4* __restrict__ xg4) {
  const size_t NX4 = (size_t)T * K / 4;
  const size_t stride = (size_t)gridDim.x * blockDim.x;
  for (size_t i = (size_t)blockIdx.x * blockDim.x + threadIdx.x; i < NX4; i += stride) {
    int p = (int)(i >> 10);
    int c = (int)(i & 1023);
    float4 v = *((const float4*)(x + (size_t)perm[p] * K) + c);
    xg4[i] = make_ushort4(f2bf(v.x), f2bf(v.y), f2bf(v.z), f2bf(v.w));
  }
}

// ------- persistent 256x256 grouped GEMM, BK=32, fp32-B DMA staging ---------
// A: bf16 from xg via global_load_lds, slab [256r][32c] bf16 (16 KB),
//    2-row-block XOR swizzle (as before).
// B: fp32 W via global_load_lds, slab [256r][32c] fp32 (32 KB), 16B-slot
//    swizzle phys = c ^ (row&7); read 2x ds_read_b128 + cvt_pk -> bf16 frags.
// 2 buffers x 48 KB = 96 KB. One {VM0; BAR} per 32-K step (stage issued at
// step start, consumed next step -> latency hidden under reads+MFMA).
__global__ __launch_bounds__(512, 2)
void gemm8p(const unsigned short* __restrict__ xg, const float* __restrict__ wf,
            const int* __restrict__ perm, const int4* __restrict__ t256,
            const int4* __restrict__ sched, float* __restrict__ out) {
  __shared__ unsigned short lds[49152];  // 96 KiB; buf b at b*24576 (ushorts)
  const int bid = blockIdx.x;
  const int tid = threadIdx.x;
  const int wid = tid >> 6, lane = tid & 63;
  const int wr = wid >> 2, wc = wid & 3;  // 2M x 4N waves; per-wave 128x64
  const int kc4 = lane >> 4;

#define GLL(gp, lp) __builtin_amdgcn_global_load_lds( \
    (const __attribute__((address_space(1))) void*)(gp), \
    (__attribute__((address_space(3))) void*)(lp), 16, 0, 0)
// A staging: 2 issues (slots 0..511, 512..1023), linear dest, pre-swz source.
#define GLLA(bo, ko) do { \
    GLL(srcA0 + (ko), &lds[(bo) + wid * 512]); \
    GLL(srcA1 + (ko), &lds[(bo) + 4096 + wid * 512]); \
  } while (0)
// B staging: 4 issues of 16B x 512 thr; dest linear at slab+j*4096 ushorts.
#define GLLB(bo, ko) do { \
    GLL(srcB0 + (ko), &lds[(bo) + 8192 + wid * 512]); \
    GLL(srcB1 + (ko), &lds[(bo) + 8192 + 4096 + wid * 512]); \
    GLL(srcB2 + (ko), &lds[(bo) + 8192 + 8192 + wid * 512]); \
    GLL(srcB3 + (ko), &lds[(bo) + 8192 + 12288 + wid * 512]); \
  } while (0)
#define LOADA(dst, bo, mh) do { _Pragma("unroll") \
    for (int mi = 0; mi < 4; ++mi) \
      dst[mi] = *(const bf16x8*)&lds[(bo) + aoff[mh][mi]]; } while (0)
#define LOADB_F(dst, bo) do { _Pragma("unroll") \
    for (int ni = 0; ni < 4; ++ni) { \
      float4 f0 = *(const float4*)&lds[(bo) + 8192 + boffF[ni][0]]; \
      float4 f1 = *(const float4*)&lds[(bo) + 8192 + boffF[ni][1]]; \
      dst[ni] = pack8(f0, f1); \
    } } while (0)
#define MFMA16(A, B, mh) do { _Pragma("unroll") \
    for (int mi = 0; mi < 4; ++mi) _Pragma("unroll") \
      for (int ni = 0; ni < 4; ++ni) \
        acc[(mh) * 4 + mi][ni] = __builtin_amdgcn_mfma_f32_16x16x32_bf16( \
            A[mi], B[ni], acc[(mh) * 4 + mi][ni], 0, 0, 0); } while (0)
#define BAR() do { __builtin_amdgcn_s_barrier(); asm volatile("" ::: "memory"); } while (0)
#define VM0() asm volatile("s_waitcnt vmcnt(0)" ::: "memory")
#define PRIO1() __builtin_amdgcn_s_setprio(1)
#define PRIO0() __builtin_amdgcn_s_setprio(0)

// One 32-K step: stage next step into XB; read+convert cur from CB; 32 MFMA.
#define STEP(CB, XB, koe) do { \
    const int ko = (koe); \
    GLLB(XB, ko); GLLA(XB, ko); \
    LOADA(afP, CB, 0); LOADA(afQ, CB, 1); \
    LOADB_F(bfP, CB); \
    PRIO1(); MFMA16(afP, bfP, 0); MFMA16(afQ, bfP, 1); PRIO0(); \
    VM0(); BAR(); \
  } while (0)

  // A swizzled fragment offsets (ushort units)
  int aoff[2][4];
#pragma unroll
  for (int mh = 0; mh < 2; ++mh)
#pragma unroll
    for (int mi = 0; mi < 4; ++mi) {
      int r = wr * 128 + mh * 64 + mi * 16 + (lane & 15);
      aoff[mh][mi] = (((r >> 1) << 3) + (((((r & 1) << 2) | kc4)) ^ ((r >> 1) & 7))) * 8;
    }
  // B fp32 fragment offsets: row*64 + (slot ^ (row&7))*8 ushorts, 2 slots
  int boffF[4][2];
#pragma unroll
  for (int ni = 0; ni < 4; ++ni) {
    int r = wc * 64 + ni * 16 + (lane & 15);
    boffF[ni][0] = r * 64 + (((2 * kc4) ^ (r & 7)) << 3);
    boffF[ni][1] = r * 64 + (((2 * kc4 + 1) ^ (r & 7)) << 3);
  }

  for (int sg = 0; sg < 3; ++sg) {
    const int4 sd = sched[bid * 3 + sg];
    if (sd.x < 0) break;
    const int4 td = t256[sd.x];
    const int e = td.x, p0 = td.y, rc = td.z, n0 = td.w;
    const int kt0 = sd.y << 3;   // first 32-K step
    const int nt = sd.z << 3;    // steps in segment (multiple of 8)

    // A staging source decode (slot -> row/c4, inverse of read swizzle)
    const unsigned short *srcA0, *srcA1;
    {
      int s0 = tid, s1 = 512 + tid;
      int b0 = s0 >> 3, v0 = (s0 & 7) ^ (b0 & 7);
      int r0 = b0 * 2 + (v0 >> 2), c0 = v0 & 3;
      int b1 = s1 >> 3, v1 = (s1 & 7) ^ (b1 & 7);
      int r1 = b1 * 2 + (v1 >> 2), c1 = v1 & 3;
      int ra0 = r0 < rc ? r0 : rc - 1;
      int ra1 = r1 < rc ? r1 : rc - 1;
      srcA0 = xg + (size_t)(p0 + ra0) * K + c0 * 8;
      srcA1 = xg + (size_t)(p0 + ra1) * K + c1 * 8;
    }
    // B staging sources: slot s = j*512+tid; row=s>>3; c=(s&7)^(row&7)
    const float *srcB0, *srcB1, *srcB2, *srcB3;
    {
      const float* wB = wf + (size_t)e * O * K + (size_t)n0 * K;
#define BSRC(j) (wB + (size_t)(((j) * 512 + tid) >> 3) * K + \
                 (((((j) * 512 + tid) & 7) ^ ((((j) * 512 + tid) >> 3) & 7)) << 2))
      srcB0 = BSRC(0); srcB1 = BSRC(1); srcB2 = BSRC(2); srcB3 = BSRC(3);
#undef BSRC
    }

    f32x4 acc[8][4] = {};
    bf16x8 afP[4], afQ[4], bfP[4];

    const int kb = kt0 << 5;
    GLLB(0, kb); GLLA(0, kb);
    VM0(); BAR();

    for (int tp = 0; tp < nt; tp += 2) {
      STEP(0, 24576, ((tp + 1 < nt ? tp + 1 : tp) + kt0) << 5);
      STEP(24576, 0, ((tp + 2 < nt ? tp + 2 : tp + 1) + kt0) << 5);
    }

    // epilogue: C layout col=lane&15, row=(lane>>4)*4+reg
    if (sd.z == 16) {
#pragma unroll
      for (int mh = 0; mh < 2; ++mh)
#pragma unroll
        for (int mi = 0; mi < 4; ++mi) {
          const int rbase = wr * 128 + mh * 64 + mi * 16 + (lane >> 4) * 4;
#pragma unroll
          for (int reg = 0; reg < 4; ++reg) {
            const int pr = rbase + reg;
            if (pr < rc) {
              float* orow = out + (size_t)perm[p0 + pr] * O + n0 + wc * 64 + (lane & 15);
#pragma unroll
              for (int ni = 0; ni < 4; ++ni) orow[ni * 16] = acc[mh * 4 + mi][ni][reg];
            }
          }
        }
    } else {
#pragma unroll
      for (int mh = 0; mh < 2; ++mh)
#pragma unroll
        for (int mi = 0; mi < 4; ++mi) {
          const int rbase = wr * 128 + mh * 64 + mi * 16 + (lane >> 4) * 4;
#pragma unroll
          for (int reg = 0; reg < 4; ++reg) {
            const int pr = rbase + reg;
            if (pr < rc) {
              float* orow = out + (size_t)perm[p0 + pr] * O + n0 + wc * 64 + (lane & 15);
#pragma unroll
              for (int ni = 0; ni < 4; ++ni)
                unsafeAtomicAdd(&orow[ni * 16], acc[mh * 4 + mi][ni][reg]);
            }
          }
        }
    }
  }
}

// ---------------- fallback (small ws): 128x128 fp32-source reg-staged ----------------
__global__ __launch_bounds__(256)
void gemm_fb(const float* __restrict__ xf, const float* __restrict__ wf,
             const int* __restrict__ perm, const int4* __restrict__ tiles,
             float* __restrict__ out) {
  __shared__ unsigned short lds_a[128 * 64];
  __shared__ unsigned short lds_b[128 * 64];
  const int4 td = tiles[blockIdx.x];
  if (td.x < 0) return;
  const int e = td.x, p0 = td.y, rc = td.z;
  const int n0 = blockIdx.y * 128;
  const int wave = threadIdx.x >> 6, lane = threadIdx.x & 63;
  const int wr = wave >> 1, wc = wave & 1;
  f32x4 acc[4][4] = {};
  const float* wf_base = wf + (size_t)e * O * K + (size_t)n0 * K;
  for (int k0 = 0; k0 < K; k0 += 64) {
    if (k0) __syncthreads();
#pragma unroll
    for (int i = 0; i < 8; i++) {
      int l4 = i * 256 + (int)threadIdx.x;
      int row = l4 >> 4;
      int c4 = (l4 & 15) << 2;
      int ra = row < rc ? row : (rc - 1);
      const float4 va = *(const float4*)(xf + (size_t)perm[p0 + ra] * K + k0 + c4);
      *(ushort4*)&lds_a[row * 64 + c4] = make_ushort4(f2bf(va.x), f2bf(va.y), f2bf(va.z), f2bf(va.w));
      const float4 vb = *(const float4*)(wf_base + (size_t)row * K + k0 + c4);
      *(ushort4*)&lds_b[row * 64 + c4] = make_ushort4(f2bf(vb.x), f2bf(vb.y), f2bf(vb.z), f2bf(vb.w));
    }
    __syncthreads();
#pragma unroll
    for (int ks = 0; ks < 2; ks++) {
      bf16x8 a2[4], b2[4];
#pragma unroll
      for (int mi = 0; mi < 4; mi++)
        a2[mi] = *(const bf16x8*)&lds_a[(wr * 64 + mi * 16 + (lane & 15)) * 64 + ks * 32 + (lane >> 4) * 8];
#pragma unroll
      for (int ni = 0; ni < 4; ni++)
        b2[ni] = *(const bf16x8*)&lds_b[(wc * 64 + ni * 16 + (lane & 15)) * 64 + ks * 32 + (lane >> 4) * 8];
#pragma unroll
      for (int mi = 0; mi < 4; mi++)
#pragma unroll
        for (int ni = 0; ni < 4; ni++)
          acc[mi][ni] = __builtin_amdgcn_mfma_f32_16x16x32_bf16(a2[mi], b2[ni], acc[mi][ni], 0, 0, 0);
    }
  }
#pragma unroll
  for (int mi = 0; mi < 4; mi++) {
    const int rb = wr * 64 + mi * 16 + (lane >> 4) * 4;
#pragma unroll
    for (int reg = 0; reg < 4; reg++) {
      const int rt = rb + reg;
      if (rt < rc) {
        float* orow = out + (size_t)perm[p0 + rt] * O + n0 + wc * 64 + (lane & 15);
#pragma unroll
        for (int ni = 0; ni < 4; ni++) orow[ni * 16] = acc[mi][ni][reg];
      }
    }
  }
}

extern "C" void kernel_launch(void* const* d_in, const int* in_sizes, int n_in,
                              void* d_out, int out_size, void* d_ws, size_t ws_size,
                              hipStream_t stream) {
  const float* x = (const float*)d_in[0];
  const float* w = (const float*)d_in[1];
  const int* idx = (const int*)d_in[2];
  float* out = (float*)d_out;
  char* ws = (char*)d_ws;

  int* perm = (int*)ws;                        // 16 KB
  int* meta = (int*)(ws + 16384);              // 16 B
  int4* t256 = (int4*)(ws + 16640);            // 4864 B
  int4* t128 = (int4*)(ws + 22528);            // 560 B
  int4* sched = (int4*)(ws + 24576);           // 12 KB
  unsigned short* xg = (unsigned short*)(ws + 65536);  // 32 MB bf16
  const size_t need = 65536 + (size_t)T * K * 2;

  build_meta<<<1, 256, 0, stream>>>(idx, perm, meta, t256, t128, sched);
  if (ws_size >= need) {
    zero_rem<<<768, 256, 0, stream>>>(meta, t256, perm, out);
    convert_x<<<1024, 256, 0, stream>>>(x, perm, (ushort4*)xg);
    gemm8p<<<256, 512, 0, stream>>>(xg, w, perm, t256, sched, out);
  } else {
    gemm_fb<<<dim3(MAXT128, 32), 256, 0, stream>>>(x, w, perm, t128, out);
  }
}

// Round 10
// 284.485 us; speedup vs baseline: 1.2049x; 1.1684x over previous
//
#include <hip/hip_runtime.h>

#define T 4096
#define K 4096
#define O 4096
#define E 4
#define BK 64
#define MAXT128 35

typedef __attribute__((ext_vector_type(8))) short bf16x8;
typedef __attribute__((ext_vector_type(4))) float f32x4;

__device__ __forceinline__ unsigned short f2bf(float f) {
  unsigned int u = __float_as_uint(f);
  u += 0x7fffu + ((u >> 16) & 1u);  // RNE
  return (unsigned short)(u >> 16);
}

// One block, 256 threads. perm, tile tables, persistent schedule
// (XCD 4x8 region map + remainder K-units; K-unit = 256 k = 4 BK-tiles).
__global__ void build_meta(const int* __restrict__ idx, int* __restrict__ perm,
                           int* __restrict__ meta, int4* __restrict__ t256,
                           int4* __restrict__ t128, int4* __restrict__ sched) {
  const int wave = threadIdx.x >> 6;
  const int lane = threadIdx.x & 63;
  __shared__ int s_off[E + 1];
  __shared__ int rtE[20], rtP[20], rtC[20];
  __shared__ int r_sh;
  int total = 0;
  for (int t0 = 0; t0 < T; t0 += 64)
    total += __popcll(__ballot(idx[t0 + lane] == wave));
  if (lane == 0) s_off[wave + 1] = total;
  __syncthreads();
  if (threadIdx.x == 0) {
    s_off[0] = 0;
    for (int e = 0; e < E; e++) s_off[e + 1] += s_off[e];
  }
  __syncthreads();
  int base = s_off[wave];
  const unsigned long long below = (1ull << lane) - 1ull;
  for (int t0 = 0; t0 < T; t0 += 64) {
    int e = idx[t0 + lane];
    unsigned long long m = __ballot(e == wave);
    if (e == wave) perm[base + __popcll(m & below)] = t0 + lane;
    base += __popcll(m);
  }
  if (threadIdx.x == 0) {
    int n = 0;
    for (int e = 0; e < E; e++) {
      int s = s_off[e], c = s_off[e + 1] - s;
      for (int ro = 0; ro < c; ro += 256) {
        rtE[n] = e; rtP[n] = s + ro; rtC[n] = (c - ro) < 256 ? (c - ro) : 256; n++;
      }
    }
    r_sh = n;
    meta[0] = n * 16;
    int n1 = 0;
    for (int e = 0; e < E; e++) {
      int s = s_off[e], c = s_off[e + 1] - s;
      for (int ro = 0; ro < c; ro += 128)
        t128[n1++] = make_int4(e, s + ro, (c - ro) < 128 ? (c - ro) : 128, 0);
    }
    for (; n1 < MAXT128; n1++) t128[n1] = make_int4(-1, 0, 0, 0);
  }
  __syncthreads();
  const int r = r_sh;  // rowtiles, 16..19
  for (int i = threadIdx.x; i < 16 * r; i += 256)
    t256[i] = make_int4(rtE[i >> 4], rtP[i >> 4], rtC[i >> 4], (i & 15) * 256);
  {
    const int b = threadIdx.x;
    const int ru = r - 16;
    const int xcd = b & 7, s = b >> 3;
    const int rt_ = 4 * (xcd >> 1) + (s >> 3);
    const int nt_ = 8 * (xcd & 1) + (s & 7);
    sched[b * 3 + 0] = make_int4(rt_ * 16 + nt_, 0, 16, 0);
    int sgi = 1, u0 = b * ru, u1 = u0 + ru;
    while (u0 < u1) {
      int tI = 256 + (u0 >> 4), q0 = u0 & 15;
      int avail = 16 - q0, want = u1 - u0;
      int take = want < avail ? want : avail;
      sched[b * 3 + sgi] = make_int4(tI, q0, take, 0);
      sgi++; u0 += take;
    }
    for (; sgi < 3; sgi++) sched[b * 3 + sgi] = make_int4(-1, 0, 0, 0);
  }
}

// Zero the output regions of remainder tiles (atomic-combine targets).
__global__ void zero_rem(const int* __restrict__ meta, const int4* __restrict__ t256,
                         const int* __restrict__ perm, float* __restrict__ out) {
  const int ntiles = meta[0];
  const int tI = 256 + (int)blockIdx.x / 16;
  if (tI >= ntiles) return;
  const int4 td = t256[tI];
  const int rt = (blockIdx.x & 15) * 16 + ((int)threadIdx.x >> 4);
  if (rt >= td.z) return;
  float4* p = (float4*)(out + (size_t)perm[td.y + rt] * O + td.w) + (threadIdx.x & 15) * 4;
  const float4 z = {0.f, 0.f, 0.f, 0.f};
  p[0] = z; p[1] = z; p[2] = z; p[3] = z;
}

// Cast W (fp32->bf16) and gather-cast x rows into expert-sorted order.
__global__ void convert_kernel(const float4* __restrict__ w4, const float* __restrict__ x,
                               const int* __restrict__ perm,
                               ushort4* __restrict__ wb4, ushort4* __restrict__ xg4) {
  const size_t NW4 = (size_t)E * O * K / 4;
  const size_t NX4 = (size_t)T * K / 4;
  const size_t stride = (size_t)gridDim.x * blockDim.x;
  for (size_t i = (size_t)blockIdx.x * blockDim.x + threadIdx.x; i < NW4 + NX4; i += stride) {
    if (i < NW4) {
      float4 v = w4[i];
      wb4[i] = make_ushort4(f2bf(v.x), f2bf(v.y), f2bf(v.z), f2bf(v.w));
    } else {
      size_t j = i - NW4;
      int p = (int)(j >> 10);
      int c = (int)(j & 1023);
      float4 v = *((const float4*)(x + (size_t)perm[p] * K) + c);
      xg4[j] = make_ushort4(f2bf(v.x), f2bf(v.y), f2bf(v.z), f2bf(v.w));
    }
  }
}

// ---------------- persistent 256x256 grouped GEMM, full-tile lookahead ------
// 256 blocks (1/CU), <=3 (tile, K-range) segments each.
// LDS: 2 buffers x 4 slabs 16KB [A.kh0][A.kh1][B.kh0][B.kh1] = 128 KiB.
// Slab = [256r][32c] bf16 as 1024 16B-slots, 2-row-block XOR swizzle.
// ALL 8 staging loads for tile t+1 issue at the START of tile t; a single
// {VM0; BAR} at tile end publishes them — every load gets a full K-tile
// (~2500-5000 cyc) to land, covering HBM-miss latency. 1 barrier/K-tile.
__global__ __launch_bounds__(512, 2)
void gemm8p(const unsigned short* __restrict__ xg, const unsigned short* __restrict__ wbb,
            const int* __restrict__ perm, const int4* __restrict__ t256,
            const int4* __restrict__ sched, float* __restrict__ out) {
  __shared__ unsigned short lds[65536];  // 128 KiB
  const int bid = blockIdx.x;
  const int tid = threadIdx.x;
  const int wid = tid >> 6, lane = tid & 63;
  const int wr = wid >> 2, wc = wid & 3;  // 2M x 4N waves; per-wave 128x64
  const int kc4 = lane >> 4;
  unsigned short* ldsw = &lds[wid * 512];  // wave-uniform stage base

#define GLL(gp, lp) __builtin_amdgcn_global_load_lds( \
    (const __attribute__((address_space(1))) void*)(gp), \
    (__attribute__((address_space(3))) void*)(lp), 16, 0, 0)
#define STAGE_A(bo, kh, ko) do { \
    GLL(srcA0 + (ko) + (kh) * 32, ldsw + (bo) + (kh) * 8192); \
    GLL(srcA1 + (ko) + (kh) * 32, ldsw + (bo) + (kh) * 8192 + 4096); \
  } while (0)
#define STAGE_B(bo, kh, ko) do { \
    GLL(srcB0 + (ko) + (kh) * 32, ldsw + (bo) + 16384 + (kh) * 8192); \
    GLL(srcB1 + (ko) + (kh) * 32, ldsw + (bo) + 16384 + (kh) * 8192 + 4096); \
  } while (0)
#define LOADA(dst, bo, ks, mh) do { _Pragma("unroll") \
    for (int mi = 0; mi < 4; ++mi) \
      dst[mi] = *(const bf16x8*)&lds[(bo) + (ks) * 8192 + aoff[mh][mi]]; } while (0)
#define LOADB(dst, bo, ks) do { _Pragma("unroll") \
    for (int ni = 0; ni < 4; ++ni) \
      dst[ni] = *(const bf16x8*)&lds[(bo) + 16384 + (ks) * 8192 + boff[ni]]; } while (0)
#define MFMA16(A, B, mh) do { _Pragma("unroll") \
    for (int mi = 0; mi < 4; ++mi) _Pragma("unroll") \
      for (int ni = 0; ni < 4; ++ni) \
        acc[(mh) * 4 + mi][ni] = __builtin_amdgcn_mfma_f32_16x16x32_bf16( \
            A[mi], B[ni], acc[(mh) * 4 + mi][ni], 0, 0, 0); } while (0)
#define BAR() do { __builtin_amdgcn_s_barrier(); asm volatile("" ::: "memory"); } while (0)
#define VM0() asm volatile("s_waitcnt vmcnt(0)" ::: "memory")
#define PRIO1() __builtin_amdgcn_s_setprio(1)
#define PRIO0() __builtin_amdgcn_s_setprio(0)

// One K-tile: issue ALL of tile t+1's staging first; read+MFMA tile t;
// one {VM0; BAR} at the end (loads are a full tile old -> no stall).
#define KTILE(C, X, koe) do { \
    const int ko = (koe); \
    STAGE_A(X, 0, ko); STAGE_B(X, 0, ko); \
    STAGE_A(X, 1, ko); STAGE_B(X, 1, ko); \
    LOADA(afP, C, 0, 0); LOADB(bfP, C, 0); \
    PRIO1(); MFMA16(afP, bfP, 0); PRIO0(); \
    LOADA(afQ, C, 0, 1); \
    PRIO1(); MFMA16(afQ, bfP, 1); PRIO0(); \
    LOADA(afP, C, 1, 0); LOADB(bfQ, C, 1); \
    PRIO1(); MFMA16(afP, bfQ, 0); PRIO0(); \
    LOADA(afQ, C, 1, 1); \
    PRIO1(); MFMA16(afQ, bfQ, 1); PRIO0(); \
    VM0(); BAR(); \
  } while (0)

  // swizzled fragment offsets (ushort units) — segment-invariant
  int aoff[2][4], boff[4];
#pragma unroll
  for (int mh = 0; mh < 2; ++mh)
#pragma unroll
    for (int mi = 0; mi < 4; ++mi) {
      int r = wr * 128 + mh * 64 + mi * 16 + (lane & 15);
      aoff[mh][mi] = (((r >> 1) << 3) + (((((r & 1) << 2) | kc4)) ^ ((r >> 1) & 7))) * 8;
    }
#pragma unroll
  for (int ni = 0; ni < 4; ++ni) {
    int r = wc * 64 + ni * 16 + (lane & 15);
    boff[ni] = (((r >> 1) << 3) + (((((r & 1) << 2) | kc4)) ^ ((r >> 1) & 7))) * 8;
  }

  for (int sg = 0; sg < 3; ++sg) {
    const int4 sd = sched[bid * 3 + sg];
    if (sd.x < 0) break;
    const int4 td = t256[sd.x];
    const int e = td.x, p0 = td.y, rc = td.z, n0 = td.w;
    const int kt0 = sd.y << 2;   // first BK-tile
    const int nt = sd.z << 2;    // BK-tiles in segment (multiple of 4)

    // staging source decode (slot -> logical row/c4, inverse of read swizzle)
    const unsigned short *srcA0, *srcA1, *srcB0, *srcB1;
    {
      const unsigned short* wB = wbb + (size_t)e * O * K + (size_t)n0 * K;
      int s0 = tid, s1 = 512 + tid;
      int b0 = s0 >> 3, v0 = (s0 & 7) ^ (b0 & 7);
      int r0 = b0 * 2 + (v0 >> 2), c0 = v0 & 3;
      int b1 = s1 >> 3, v1 = (s1 & 7) ^ (b1 & 7);
      int r1 = b1 * 2 + (v1 >> 2), c1 = v1 & 3;
      int ra0 = r0 < rc ? r0 : rc - 1;
      int ra1 = r1 < rc ? r1 : rc - 1;
      srcA0 = xg + (size_t)(p0 + ra0) * K + c0 * 8;
      srcA1 = xg + (size_t)(p0 + ra1) * K + c1 * 8;
      srcB0 = wB + (size_t)r0 * K + c0 * 8;
      srcB1 = wB + (size_t)r1 * K + c1 * 8;
    }

    f32x4 acc[8][4] = {};
    bf16x8 afP[4], afQ[4], bfP[4], bfQ[4];

    const int kb = kt0 << 6;
    STAGE_A(0, 0, kb); STAGE_B(0, 0, kb);
    STAGE_A(0, 1, kb); STAGE_B(0, 1, kb);
    VM0(); BAR();

    for (int tp = 0; tp < nt; tp += 2) {
      KTILE(0, 32768, ((tp + 1 < nt ? tp + 1 : tp) + kt0) << 6);
      KTILE(32768, 0, ((tp + 2 < nt ? tp + 2 : tp + 1) + kt0) << 6);
    }

    // epilogue: C layout col=lane&15, row=(lane>>4)*4+reg
    if (sd.z == 16) {
#pragma unroll
      for (int mh = 0; mh < 2; ++mh)
#pragma unroll
        for (int mi = 0; mi < 4; ++mi) {
          const int rbase = wr * 128 + mh * 64 + mi * 16 + (lane >> 4) * 4;
#pragma unroll
          for (int reg = 0; reg < 4; ++reg) {
            const int pr = rbase + reg;
            if (pr < rc) {
              float* orow = out + (size_t)perm[p0 + pr] * O + n0 + wc * 64 + (lane & 15);
#pragma unroll
              for (int ni = 0; ni < 4; ++ni) orow[ni * 16] = acc[mh * 4 + mi][ni][reg];
            }
          }
        }
    } else {
#pragma unroll
      for (int mh = 0; mh < 2; ++mh)
#pragma unroll
        for (int mi = 0; mi < 4; ++mi) {
          const int rbase = wr * 128 + mh * 64 + mi * 16 + (lane >> 4) * 4;
#pragma unroll
          for (int reg = 0; reg < 4; ++reg) {
            const int pr = rbase + reg;
            if (pr < rc) {
              float* orow = out + (size_t)perm[p0 + pr] * O + n0 + wc * 64 + (lane & 15);
#pragma unroll
              for (int ni = 0; ni < 4; ++ni)
                unsafeAtomicAdd(&orow[ni * 16], acc[mh * 4 + mi][ni][reg]);
            }
          }
        }
    }
  }
}

// ---------------- fallback (small ws): 128x128 fp32-source reg-staged ----------------
__global__ __launch_bounds__(256)
void gemm_fb(const float* __restrict__ xf, const float* __restrict__ wf,
             const int* __restrict__ perm, const int4* __restrict__ tiles,
             float* __restrict__ out) {
  __shared__ unsigned short lds_a[128 * 64];
  __shared__ unsigned short lds_b[128 * 64];
  const int4 td = tiles[blockIdx.x];
  if (td.x < 0) return;
  const int e = td.x, p0 = td.y, rc = td.z;
  const int n0 = blockIdx.y * 128;
  const int wave = threadIdx.x >> 6, lane = threadIdx.x & 63;
  const int wr = wave >> 1, wc = wave & 1;
  f32x4 acc[4][4] = {};
  const float* wf_base = wf + (size_t)e * O * K + (size_t)n0 * K;
  for (int k0 = 0; k0 < K; k0 += 64) {
    if (k0) __syncthreads();
#pragma unroll
    for (int i = 0; i < 8; i++) {
      int l4 = i * 256 + (int)threadIdx.x;
      int row = l4 >> 4;
      int c4 = (l4 & 15) << 2;
      int ra = row < rc ? row : (rc - 1);
      const float4 va = *(const float4*)(xf + (size_t)perm[p0 + ra] * K + k0 + c4);
      *(ushort4*)&lds_a[row * 64 + c4] = make_ushort4(f2bf(va.x), f2bf(va.y), f2bf(va.z), f2bf(va.w));
      const float4 vb = *(const float4*)(wf_base + (size_t)row * K + k0 + c4);
      *(ushort4*)&lds_b[row * 64 + c4] = make_ushort4(f2bf(vb.x), f2bf(vb.y), f2bf(vb.z), f2bf(vb.w));
    }
    __syncthreads();
#pragma unroll
    for (int ks = 0; ks < 2; ks++) {
      bf16x8 a2[4], b2[4];
#pragma unroll
      for (int mi = 0; mi < 4; mi++)
        a2[mi] = *(const bf16x8*)&lds_a[(wr * 64 + mi * 16 + (lane & 15)) * 64 + ks * 32 + (lane >> 4) * 8];
#pragma unroll
      for (int ni = 0; ni < 4; ni++)
        b2[ni] = *(const bf16x8*)&lds_b[(wc * 64 + ni * 16 + (lane & 15)) * 64 + ks * 32 + (lane >> 4) * 8];
#pragma unroll
      for (int mi = 0; mi < 4; mi++)
#pragma unroll
        for (int ni = 0; ni < 4; ni++)
          acc[mi][ni] = __builtin_amdgcn_mfma_f32_16x16x32_bf16(a2[mi], b2[ni], acc[mi][ni], 0, 0, 0);
    }
  }
#pragma unroll
  for (int mi = 0; mi < 4; mi++) {
    const int rb = wr * 64 + mi * 16 + (lane >> 4) * 4;
#pragma unroll
    for (int reg = 0; reg < 4; reg++) {
      const int rt = rb + reg;
      if (rt < rc) {
        float* orow = out + (size_t)perm[p0 + rt] * O + n0 + wc * 64 + (lane & 15);
#pragma unroll
        for (int ni = 0; ni < 4; ni++) orow[ni * 16] = acc[mi][ni][reg];
      }
    }
  }
}

extern "C" void kernel_launch(void* const* d_in, const int* in_sizes, int n_in,
                              void* d_out, int out_size, void* d_ws, size_t ws_size,
                              hipStream_t stream) {
  const float* x = (const float*)d_in[0];
  const float* w = (const float*)d_in[1];
  const int* idx = (const int*)d_in[2];
  float* out = (float*)d_out;
  char* ws = (char*)d_ws;

  int* perm = (int*)ws;                        // 16 KB
  int* meta = (int*)(ws + 16384);              // 16 B
  int4* t256 = (int4*)(ws + 16640);            // 4864 B
  int4* t128 = (int4*)(ws + 22528);            // 560 B
  int4* sched = (int4*)(ws + 24576);           // 12 KB
  unsigned short* xg = (unsigned short*)(ws + 65536);          // 32 MB bf16
  unsigned short* wb = xg + (size_t)T * K;                     // 128 MB bf16
  const size_t need = 65536 + (size_t)T * K * 2 + (size_t)E * O * K * 2;

  build_meta<<<1, 256, 0, stream>>>(idx, perm, meta, t256, t128, sched);
  if (ws_size >= need) {
    zero_rem<<<768, 256, 0, stream>>>(meta, t256, perm, out);
    convert_kernel<<<2048, 256, 0, stream>>>((const float4*)w, x, perm,
                                             (ushort4*)wb, (ushort4*)xg);
    gemm8p<<<256, 512, 0, stream>>>(xg, wb, perm, t256, sched, out);
  } else {
    gemm_fb<<<dim3(MAXT128, 32), 256, 0, stream>>>(x, w, perm, t128, out);
  }
}

// Round 11
// 269.283 us; speedup vs baseline: 1.2729x; 1.0565x over previous
//
#include <hip/hip_runtime.h>

#define T 4096
#define K 4096
#define O 4096
#define E 4
#define BK 64
#define MAXT128 35

typedef __attribute__((ext_vector_type(8))) short bf16x8;
typedef __attribute__((ext_vector_type(4))) float f32x4;

__device__ __forceinline__ unsigned short f2bf(float f) {
  unsigned int u = __float_as_uint(f);
  u += 0x7fffu + ((u >> 16) & 1u);  // RNE
  return (unsigned short)(u >> 16);
}

// One block, 256 threads. perm, tile tables, persistent schedule
// (XCD 4x8 region map + remainder K-units; K-unit = 256 k = 4 BK-tiles).
__global__ void build_meta(const int* __restrict__ idx, int* __restrict__ perm,
                           int* __restrict__ meta, int4* __restrict__ t256,
                           int4* __restrict__ t128, int4* __restrict__ sched) {
  const int wave = threadIdx.x >> 6;
  const int lane = threadIdx.x & 63;
  __shared__ int s_off[E + 1];
  __shared__ int rtE[20], rtP[20], rtC[20];
  __shared__ int r_sh;
  int total = 0;
  for (int t0 = 0; t0 < T; t0 += 64)
    total += __popcll(__ballot(idx[t0 + lane] == wave));
  if (lane == 0) s_off[wave + 1] = total;
  __syncthreads();
  if (threadIdx.x == 0) {
    s_off[0] = 0;
    for (int e = 0; e < E; e++) s_off[e + 1] += s_off[e];
  }
  __syncthreads();
  int base = s_off[wave];
  const unsigned long long below = (1ull << lane) - 1ull;
  for (int t0 = 0; t0 < T; t0 += 64) {
    int e = idx[t0 + lane];
    unsigned long long m = __ballot(e == wave);
    if (e == wave) perm[base + __popcll(m & below)] = t0 + lane;
    base += __popcll(m);
  }
  if (threadIdx.x == 0) {
    int n = 0;
    for (int e = 0; e < E; e++) {
      int s = s_off[e], c = s_off[e + 1] - s;
      for (int ro = 0; ro < c; ro += 256) {
        rtE[n] = e; rtP[n] = s + ro; rtC[n] = (c - ro) < 256 ? (c - ro) : 256; n++;
      }
    }
    r_sh = n;
    meta[0] = n * 16;
    int n1 = 0;
    for (int e = 0; e < E; e++) {
      int s = s_off[e], c = s_off[e + 1] - s;
      for (int ro = 0; ro < c; ro += 128)
        t128[n1++] = make_int4(e, s + ro, (c - ro) < 128 ? (c - ro) : 128, 0);
    }
    for (; n1 < MAXT128; n1++) t128[n1] = make_int4(-1, 0, 0, 0);
  }
  __syncthreads();
  const int r = r_sh;  // rowtiles, 16..19
  for (int i = threadIdx.x; i < 16 * r; i += 256)
    t256[i] = make_int4(rtE[i >> 4], rtP[i >> 4], rtC[i >> 4], (i & 15) * 256);
  {
    const int b = threadIdx.x;
    const int ru = r - 16;
    const int xcd = b & 7, s = b >> 3;
    const int rt_ = 4 * (xcd >> 1) + (s >> 3);
    const int nt_ = 8 * (xcd & 1) + (s & 7);
    sched[b * 3 + 0] = make_int4(rt_ * 16 + nt_, 0, 16, 0);
    int sgi = 1, u0 = b * ru, u1 = u0 + ru;
    while (u0 < u1) {
      int tI = 256 + (u0 >> 4), q0 = u0 & 15;
      int avail = 16 - q0, want = u1 - u0;
      int take = want < avail ? want : avail;
      sched[b * 3 + sgi] = make_int4(tI, q0, take, 0);
      sgi++; u0 += take;
    }
    for (; sgi < 3; sgi++) sched[b * 3 + sgi] = make_int4(-1, 0, 0, 0);
  }
}

// Zero the output regions of remainder tiles (atomic-combine targets).
__global__ void zero_rem(const int* __restrict__ meta, const int4* __restrict__ t256,
                         const int* __restrict__ perm, float* __restrict__ out) {
  const int ntiles = meta[0];
  const int tI = 256 + (int)blockIdx.x / 16;
  if (tI >= ntiles) return;
  const int4 td = t256[tI];
  const int rt = (blockIdx.x & 15) * 16 + ((int)threadIdx.x >> 4);
  if (rt >= td.z) return;
  float4* p = (float4*)(out + (size_t)perm[td.y + rt] * O + td.w) + (threadIdx.x & 15) * 4;
  const float4 z = {0.f, 0.f, 0.f, 0.f};
  p[0] = z; p[1] = z; p[2] = z; p[3] = z;
}

// Cast W (fp32->bf16) and gather-cast x rows into expert-sorted order.
// Split branch-free loops (W path is 80% of iterations); 4096 blocks.
__global__ void convert_kernel(const float4* __restrict__ w4, const float* __restrict__ x,
                               const int* __restrict__ perm,
                               ushort4* __restrict__ wb4, ushort4* __restrict__ xg4) {
  const size_t NW4 = (size_t)E * O * K / 4;
  const size_t NX4 = (size_t)T * K / 4;
  const size_t stride = (size_t)gridDim.x * blockDim.x;
  const size_t t0 = (size_t)blockIdx.x * blockDim.x + threadIdx.x;
  for (size_t i = t0; i < NW4; i += stride) {
    float4 v = w4[i];
    wb4[i] = make_ushort4(f2bf(v.x), f2bf(v.y), f2bf(v.z), f2bf(v.w));
  }
  for (size_t j = t0; j < NX4; j += stride) {
    int p = (int)(j >> 10);
    int c = (int)(j & 1023);
    float4 v = *((const float4*)(x + (size_t)perm[p] * K) + c);
    xg4[j] = make_ushort4(f2bf(v.x), f2bf(v.y), f2bf(v.z), f2bf(v.w));
  }
}

// ---------------- persistent 256x256 minimal-sync grouped GEMM (16x16x32) ---
// 256 blocks (1/CU), each runs <=3 (tile, K-range) segments from sched.
// LDS per buffer: 4 slabs of 16KB [A.kh0][A.kh1][B.kh0][B.kh1], 2 buffers.
// Slab = [256 rows][32 bf16] as 1024 16B-slots, 2-row-block XOR swizzle.
// MINIMAL SYNC: exactly 2 {counted-vmcnt; barrier} points per K-tile (the
// publications of the two staged halves). No lgkm drains: compiler emits
// per-dependency counted lgkmcnt; wave skew overlaps one wave's LDS read
// storm with co-resident waves' MFMA storms (setprio arbitrates).
__global__ __launch_bounds__(512, 2)
void gemm8p(const unsigned short* __restrict__ xg, const unsigned short* __restrict__ wbb,
            const int* __restrict__ perm, const int4* __restrict__ t256,
            const int4* __restrict__ sched, float* __restrict__ out) {
  __shared__ unsigned short lds[65536];  // 128 KiB
  const int bid = blockIdx.x;
  const int tid = threadIdx.x;
  const int wid = tid >> 6, lane = tid & 63;
  const int wr = wid >> 2, wc = wid & 3;  // 2M x 4N waves; per-wave 128x64
  const int kc4 = lane >> 4;
  unsigned short* ldsw = &lds[wid * 512];  // wave-uniform stage base

#define GLL(gp, lp) __builtin_amdgcn_global_load_lds( \
    (const __attribute__((address_space(1))) void*)(gp), \
    (__attribute__((address_space(3))) void*)(lp), 16, 0, 0)
#define STAGE_A(bo, kh, ko) do { \
    GLL(srcA0 + (ko) + (kh) * 32, ldsw + (bo) + (kh) * 8192); \
    GLL(srcA1 + (ko) + (kh) * 32, ldsw + (bo) + (kh) * 8192 + 4096); \
  } while (0)
#define STAGE_B(bo, kh, ko) do { \
    GLL(srcB0 + (ko) + (kh) * 32, ldsw + (bo) + 16384 + (kh) * 8192); \
    GLL(srcB1 + (ko) + (kh) * 32, ldsw + (bo) + 16384 + (kh) * 8192 + 4096); \
  } while (0)
#define LOADA(dst, bo, ks, mh) do { _Pragma("unroll") \
    for (int mi = 0; mi < 4; ++mi) \
      dst[mi] = *(const bf16x8*)&lds[(bo) + (ks) * 8192 + aoff[mh][mi]]; } while (0)
#define LOADB(dst, bo, ks) do { _Pragma("unroll") \
    for (int ni = 0; ni < 4; ++ni) \
      dst[ni] = *(const bf16x8*)&lds[(bo) + 16384 + (ks) * 8192 + boff[ni]]; } while (0)
#define MFMA16(A, B, mh) do { _Pragma("unroll") \
    for (int mi = 0; mi < 4; ++mi) _Pragma("unroll") \
      for (int ni = 0; ni < 4; ++ni) \
        acc[(mh) * 4 + mi][ni] = __builtin_amdgcn_mfma_f32_16x16x32_bf16( \
            A[mi], B[ni], acc[(mh) * 4 + mi][ni], 0, 0, 0); } while (0)
#define BAR() do { __builtin_amdgcn_s_barrier(); asm volatile("" ::: "memory"); } while (0)
#define VM4() asm volatile("s_waitcnt vmcnt(4)" ::: "memory")
#define VM0() asm volatile("s_waitcnt vmcnt(0)" ::: "memory")
#define PRIO1() __builtin_amdgcn_s_setprio(1)
#define PRIO0() __builtin_amdgcn_s_setprio(0)

// One K-tile = 2 scheduling regions, each ends with its half-publication.
// Sync#1 drains prev-tile A1,B1 (cur.kh1 published for half 2).
// Sync#2 drains this tile's A0x,B0x (nxt.kh0 published for next tile).
#define KTILE(C, X, koe) do { \
    const int ko = (koe); \
    LOADA(afP, C, 0, 0); LOADB(bfP, C, 0); \
    STAGE_A(X, 0, ko); \
    PRIO1(); MFMA16(afP, bfP, 0); PRIO0(); \
    LOADA(afQ, C, 0, 1); \
    STAGE_B(X, 0, ko); \
    PRIO1(); MFMA16(afQ, bfP, 1); PRIO0(); \
    VM4(); BAR(); \
    LOADA(afP, C, 1, 0); LOADB(bfQ, C, 1); \
    STAGE_A(X, 1, ko); \
    PRIO1(); MFMA16(afP, bfQ, 0); PRIO0(); \
    LOADA(afQ, C, 1, 1); \
    STAGE_B(X, 1, ko); \
    PRIO1(); MFMA16(afQ, bfQ, 1); PRIO0(); \
    VM4(); BAR(); \
  } while (0)

  // swizzled fragment offsets (ushort units) — segment-invariant
  int aoff[2][4], boff[4];
#pragma unroll
  for (int mh = 0; mh < 2; ++mh)
#pragma unroll
    for (int mi = 0; mi < 4; ++mi) {
      int r = wr * 128 + mh * 64 + mi * 16 + (lane & 15);
      aoff[mh][mi] = (((r >> 1) << 3) + (((((r & 1) << 2) | kc4)) ^ ((r >> 1) & 7))) * 8;
    }
#pragma unroll
  for (int ni = 0; ni < 4; ++ni) {
    int r = wc * 64 + ni * 16 + (lane & 15);
    boff[ni] = (((r >> 1) << 3) + (((((r & 1) << 2) | kc4)) ^ ((r >> 1) & 7))) * 8;
  }

  for (int sg = 0; sg < 3; ++sg) {
    const int4 sd = sched[bid * 3 + sg];
    if (sd.x < 0) break;
    const int4 td = t256[sd.x];
    const int e = td.x, p0 = td.y, rc = td.z, n0 = td.w;
    const int kt0 = sd.y << 2;   // first BK-tile
    const int nt = sd.z << 2;    // BK-tiles in segment (multiple of 4)

    // staging source decode (slot -> logical row/c4, inverse of read swizzle)
    const unsigned short *srcA0, *srcA1, *srcB0, *srcB1;
    {
      const unsigned short* wB = wbb + (size_t)e * O * K + (size_t)n0 * K;
      int s0 = tid, s1 = 512 + tid;
      int b0 = s0 >> 3, v0 = (s0 & 7) ^ (b0 & 7);
      int r0 = b0 * 2 + (v0 >> 2), c0 = v0 & 3;
      int b1 = s1 >> 3, v1 = (s1 & 7) ^ (b1 & 7);
      int r1 = b1 * 2 + (v1 >> 2), c1 = v1 & 3;
      int ra0 = r0 < rc ? r0 : rc - 1;
      int ra1 = r1 < rc ? r1 : rc - 1;
      srcA0 = xg + (size_t)(p0 + ra0) * K + c0 * 8;
      srcA1 = xg + (size_t)(p0 + ra1) * K + c1 * 8;
      srcB0 = wB + (size_t)r0 * K + c0 * 8;
      srcB1 = wB + (size_t)r1 * K + c1 * 8;
    }

    f32x4 acc[8][4] = {};
    bf16x8 afP[4], afQ[4], bfP[4], bfQ[4];

    const int kb = kt0 << 6;
    STAGE_A(0, 0, kb); STAGE_B(0, 0, kb);
    STAGE_A(0, 1, kb); STAGE_B(0, 1, kb);
    VM4(); BAR();   // kh0 published; kh1 (A1,B1) drains at first in-loop sync

    for (int tp = 0; tp < nt; tp += 2) {
      KTILE(0, 32768, ((tp + 1 < nt ? tp + 1 : tp) + kt0) << 6);
      KTILE(32768, 0, ((tp + 2 < nt ? tp + 2 : tp + 1) + kt0) << 6);
    }
    VM0();  // drain stale prefetch before epilogue / next segment's staging

    // epilogue: C layout col=lane&15, row=(lane>>4)*4+reg
    if (sd.z == 16) {
#pragma unroll
      for (int mh = 0; mh < 2; ++mh)
#pragma unroll
        for (int mi = 0; mi < 4; ++mi) {
          const int rbase = wr * 128 + mh * 64 + mi * 16 + (lane >> 4) * 4;
#pragma unroll
          for (int reg = 0; reg < 4; ++reg) {
            const int pr = rbase + reg;
            if (pr < rc) {
              float* orow = out + (size_t)perm[p0 + pr] * O + n0 + wc * 64 + (lane & 15);
#pragma unroll
              for (int ni = 0; ni < 4; ++ni) orow[ni * 16] = acc[mh * 4 + mi][ni][reg];
            }
          }
        }
    } else {
#pragma unroll
      for (int mh = 0; mh < 2; ++mh)
#pragma unroll
        for (int mi = 0; mi < 4; ++mi) {
          const int rbase = wr * 128 + mh * 64 + mi * 16 + (lane >> 4) * 4;
#pragma unroll
          for (int reg = 0; reg < 4; ++reg) {
            const int pr = rbase + reg;
            if (pr < rc) {
              float* orow = out + (size_t)perm[p0 + pr] * O + n0 + wc * 64 + (lane & 15);
#pragma unroll
              for (int ni = 0; ni < 4; ++ni)
                unsafeAtomicAdd(&orow[ni * 16], acc[mh * 4 + mi][ni][reg]);
            }
          }
        }
    }
  }
}

// ---------------- fallback (small ws): 128x128 fp32-source reg-staged ----------------
__global__ __launch_bounds__(256)
void gemm_fb(const float* __restrict__ xf, const float* __restrict__ wf,
             const int* __restrict__ perm, const int4* __restrict__ tiles,
             float* __restrict__ out) {
  __shared__ unsigned short lds_a[128 * 64];
  __shared__ unsigned short lds_b[128 * 64];
  const int4 td = tiles[blockIdx.x];
  if (td.x < 0) return;
  const int e = td.x, p0 = td.y, rc = td.z;
  const int n0 = blockIdx.y * 128;
  const int wave = threadIdx.x >> 6, lane = threadIdx.x & 63;
  const int wr = wave >> 1, wc = wave & 1;
  f32x4 acc[4][4] = {};
  const float* wf_base = wf + (size_t)e * O * K + (size_t)n0 * K;
  for (int k0 = 0; k0 < K; k0 += 64) {
    if (k0) __syncthreads();
#pragma unroll
    for (int i = 0; i < 8; i++) {
      int l4 = i * 256 + (int)threadIdx.x;
      int row = l4 >> 4;
      int c4 = (l4 & 15) << 2;
      int ra = row < rc ? row : (rc - 1);
      const float4 va = *(const float4*)(xf + (size_t)perm[p0 + ra] * K + k0 + c4);
      *(ushort4*)&lds_a[row * 64 + c4] = make_ushort4(f2bf(va.x), f2bf(va.y), f2bf(va.z), f2bf(va.w));
      const float4 vb = *(const float4*)(wf_base + (size_t)row * K + k0 + c4);
      *(ushort4*)&lds_b[row * 64 + c4] = make_ushort4(f2bf(vb.x), f2bf(vb.y), f2bf(vb.z), f2bf(vb.w));
    }
    __syncthreads();
#pragma unroll
    for (int ks = 0; ks < 2; ks++) {
      bf16x8 a2[4], b2[4];
#pragma unroll
      for (int mi = 0; mi < 4; mi++)
        a2[mi] = *(const bf16x8*)&lds_a[(wr * 64 + mi * 16 + (lane & 15)) * 64 + ks * 32 + (lane >> 4) * 8];
#pragma unroll
      for (int ni = 0; ni < 4; ni++)
        b2[ni] = *(const bf16x8*)&lds_b[(wc * 64 + ni * 16 + (lane & 15)) * 64 + ks * 32 + (lane >> 4) * 8];
#pragma unroll
      for (int mi = 0; mi < 4; mi++)
#pragma unroll
        for (int ni = 0; ni < 4; ni++)
          acc[mi][ni] = __builtin_amdgcn_mfma_f32_16x16x32_bf16(a2[mi], b2[ni], acc[mi][ni], 0, 0, 0);
    }
  }
#pragma unroll
  for (int mi = 0; mi < 4; mi++) {
    const int rb = wr * 64 + mi * 16 + (lane >> 4) * 4;
#pragma unroll
    for (int reg = 0; reg < 4; reg++) {
      const int rt = rb + reg;
      if (rt < rc) {
        float* orow = out + (size_t)perm[p0 + rt] * O + n0 + wc * 64 + (lane & 15);
#pragma unroll
        for (int ni = 0; ni < 4; ni++) orow[ni * 16] = acc[mi][ni][reg];
      }
    }
  }
}

extern "C" void kernel_launch(void* const* d_in, const int* in_sizes, int n_in,
                              void* d_out, int out_size, void* d_ws, size_t ws_size,
                              hipStream_t stream) {
  const float* x = (const float*)d_in[0];
  const float* w = (const float*)d_in[1];
  const int* idx = (const int*)d_in[2];
  float* out = (float*)d_out;
  char* ws = (char*)d_ws;

  int* perm = (int*)ws;                        // 16 KB
  int* meta = (int*)(ws + 16384);              // 16 B
  int4* t256 = (int4*)(ws + 16640);            // 4864 B
  int4* t128 = (int4*)(ws + 22528);            // 560 B
  int4* sched = (int4*)(ws + 24576);           // 12 KB
  unsigned short* xg = (unsigned short*)(ws + 65536);          // 32 MB bf16
  unsigned short* wb = xg + (size_t)T * K;                     // 128 MB bf16
  const size_t need = 65536 + (size_t)T * K * 2 + (size_t)E * O * K * 2;

  build_meta<<<1, 256, 0, stream>>>(idx, perm, meta, t256, t128, sched);
  if (ws_size >= need) {
    zero_rem<<<768, 256, 0, stream>>>(meta, t256, perm, out);
    convert_kernel<<<4096, 256, 0, stream>>>((const float4*)w, x, perm,
                                             (ushort4*)wb, (ushort4*)xg);
    gemm8p<<<256, 512, 0, stream>>>(xg, wb, perm, t256, sched, out);
  } else {
    gemm_fb<<<dim3(MAXT128, 32), 256, 0, stream>>>(x, w, perm, t128, out);
  }
}